// Round 1
// baseline (529.851 us; speedup 1.0000x reference)
//
#include <hip/hip_runtime.h>
#include <hip/hip_bf16.h>

#define D_MODEL 1024
#define NHEADS 16
#define DEPTH 64
#define BATCH 2
#define SEQ 2048
#define NTOK (BATCH * SEQ)

typedef short bf16x8 __attribute__((ext_vector_type(8)));
typedef float f32x4 __attribute__((ext_vector_type(4)));
typedef unsigned short ushortx8 __attribute__((ext_vector_type(8)));

__device__ __forceinline__ unsigned short f2bf(float f) {
    union { float f; unsigned u; } v; v.f = f;
    unsigned r = v.u + 0x7fffu + ((v.u >> 16) & 1u);
    return (unsigned short)(r >> 16);
}

// C[M,N] = A[M,K] * B[N,K]^T + bias.  B is always fp32 (a weight matrix).
// DEST 0: write bf16 head-split [B, H, S, DEPTH]   (M = B*SEQ tokens, N = D_MODEL)
// DEST 1: write fp32 flat [M, N]
template<bool A_F32, int DEST>
__global__ __launch_bounds__(256) void gemm_bt(
    const void* __restrict__ Ap, const float* __restrict__ Bp,
    const float* __restrict__ bias, void* __restrict__ Cp,
    int M, int N, int K)
{
    __shared__ unsigned short As[128][40];   // +8 pad: conflict-free b128 reads
    __shared__ unsigned short Bs[128][40];

    const int tid  = threadIdx.x;
    const int lane = tid & 63;
    const int w    = tid >> 6;
    const int wr   = w >> 1, wc = w & 1;     // 2x2 wave grid, 64x64 per wave
    const int lr   = lane & 15, lg = lane >> 4;

    const int row0 = blockIdx.y * 128;
    const int n0   = blockIdx.x * 128;

    f32x4 acc[4][4];
    for (int i = 0; i < 4; ++i)
        for (int j = 0; j < 4; ++j)
            for (int r = 0; r < 4; ++r) acc[i][j][r] = 0.f;

    for (int kt = 0; kt < K; kt += 32) {
        // ---- stage A tile [128 x 32] ----
        if (A_F32) {
            const float* A = (const float*)Ap;
            for (int c = tid; c < 1024; c += 256) {
                int r = c >> 3, col = (c & 7) * 4;
                float4 vv = *(const float4*)&A[(size_t)(row0 + r) * K + kt + col];
                As[r][col + 0] = f2bf(vv.x);
                As[r][col + 1] = f2bf(vv.y);
                As[r][col + 2] = f2bf(vv.z);
                As[r][col + 3] = f2bf(vv.w);
            }
        } else {
            const unsigned short* A = (const unsigned short*)Ap;
            for (int c = tid; c < 512; c += 256) {
                int r = c >> 2, col = (c & 3) * 8;
                ushortx8 vv = *(const ushortx8*)&A[(size_t)(row0 + r) * K + kt + col];
                *(ushortx8*)&As[r][col] = vv;
            }
        }
        // ---- stage B tile [128 x 32] (fp32 weights) ----
        for (int c = tid; c < 1024; c += 256) {
            int r = c >> 3, col = (c & 7) * 4;
            float4 vv = *(const float4*)&Bp[(size_t)(n0 + r) * K + kt + col];
            Bs[r][col + 0] = f2bf(vv.x);
            Bs[r][col + 1] = f2bf(vv.y);
            Bs[r][col + 2] = f2bf(vv.z);
            Bs[r][col + 3] = f2bf(vv.w);
        }
        __syncthreads();

        bf16x8 af[4], bfr[4];
        for (int i = 0; i < 4; ++i)
            af[i] = *(const bf16x8*)&As[wr * 64 + i * 16 + lr][lg * 8];
        for (int j = 0; j < 4; ++j)
            bfr[j] = *(const bf16x8*)&Bs[wc * 64 + j * 16 + lr][lg * 8];
        for (int i = 0; i < 4; ++i)
            for (int j = 0; j < 4; ++j)
                acc[i][j] = __builtin_amdgcn_mfma_f32_16x16x32_bf16(
                    af[i], bfr[j], acc[i][j], 0, 0, 0);
        __syncthreads();
    }

    // ---- epilogue: C row = lg*4 + r, col = lr (verified m89/m91 mapping) ----
    for (int i = 0; i < 4; ++i) {
        for (int j = 0; j < 4; ++j) {
            int gcol = n0 + wc * 64 + j * 16 + lr;
            float bv = bias[gcol];
            for (int r = 0; r < 4; ++r) {
                int grow = row0 + wr * 64 + i * 16 + lg * 4 + r;
                float val = acc[i][j][r] + bv;
                if (DEST == 0) {
                    int b = grow >> 11, s = grow & (SEQ - 1);
                    int h = gcol >> 6, dh = gcol & 63;
                    ((unsigned short*)Cp)[(((size_t)b * NHEADS + h) * SEQ + s) * DEPTH + dh]
                        = f2bf(val);
                } else {
                    ((float*)Cp)[(size_t)grow * N + gcol] = val;
                }
            }
        }
    }
}

// Causal flash attention over head-split bf16 Q/K/V [B,H,S,64] -> ctx bf16 [B,S,D_MODEL]
__global__ __launch_bounds__(256) void attn_causal(
    const unsigned short* __restrict__ Qh, const unsigned short* __restrict__ Kh,
    const unsigned short* __restrict__ Vh, unsigned short* __restrict__ ctx)
{
    const int qt = blockIdx.x;           // Q tile of 64 rows
    const int bh = blockIdx.y;           // b*16 + h
    const int tid  = threadIdx.x;
    const int w    = tid >> 6;           // wave: rows w*16 .. w*16+15
    const int lane = tid & 63;
    const int lr   = lane & 15, lg = lane >> 4;

    __shared__ unsigned short Kl[64][72];     // +8 pad
    __shared__ unsigned short Vt[64][72];     // transposed: Vt[d][t]
    __shared__ unsigned short Pl[4][16][72];  // per-wave P tile

    const unsigned short* Qbase = Qh + ((size_t)bh * SEQ + qt * 64) * DEPTH;
    const unsigned short* Kbase = Kh + (size_t)bh * SEQ * DEPTH;
    const unsigned short* Vbase = Vh + (size_t)bh * SEQ * DEPTH;

    // Q fragments: A layout, row = lr, k = kk*32 + lg*8
    bf16x8 qf[2];
    for (int kk = 0; kk < 2; ++kk)
        qf[kk] = *(const bf16x8*)&Qbase[(size_t)(w * 16 + lr) * DEPTH + kk * 32 + lg * 8];

    f32x4 oacc[4];
    for (int dn = 0; dn < 4; ++dn)
        for (int r = 0; r < 4; ++r) oacc[dn][r] = 0.f;
    float mrun[4] = {-1e30f, -1e30f, -1e30f, -1e30f};
    float lrun[4] = {0.f, 0.f, 0.f, 0.f};

    for (int jt = 0; jt <= qt; ++jt) {
        const unsigned short* Kt = Kbase + (size_t)jt * 64 * DEPTH;
        const unsigned short* Vg = Vbase + (size_t)jt * 64 * DEPTH;

        // stage K tile [64 t][64 d]
        for (int c = tid; c < 512; c += 256) {
            int r = c >> 3, col = (c & 7) * 8;
            ushortx8 vv = *(const ushortx8*)&Kt[r * 64 + col];
            *(ushortx8*)&Kl[r][col] = vv;
        }
        // stage V transposed: Vt[d][t]
        {
            int t = tid & 63, d0 = (tid >> 6) * 16;
            ushortx8 v0 = *(const ushortx8*)&Vg[t * 64 + d0];
            ushortx8 v1 = *(const ushortx8*)&Vg[t * 64 + d0 + 8];
            for (int i = 0; i < 8; ++i) Vt[d0 + i][t] = v0[i];
            for (int i = 0; i < 8; ++i) Vt[d0 + 8 + i][t] = v1[i];
        }
        __syncthreads();

        // S = Q K^T / 8  (per wave: 16 m x 64 t)
        f32x4 s[4];
        for (int tn = 0; tn < 4; ++tn) {
            f32x4 a;
            for (int r = 0; r < 4; ++r) a[r] = 0.f;
            for (int kk = 0; kk < 2; ++kk) {
                bf16x8 kf = *(const bf16x8*)&Kl[tn * 16 + lr][kk * 32 + lg * 8];
                a = __builtin_amdgcn_mfma_f32_16x16x32_bf16(qf[kk], kf, a, 0, 0, 0);
            }
            for (int r = 0; r < 4; ++r) s[tn][r] = a[r] * 0.125f;
        }

        // causal mask on diagonal tile only
        if (jt == qt) {
            for (int tn = 0; tn < 4; ++tn) {
                int t = tn * 16 + lr;
                for (int r = 0; r < 4; ++r) {
                    int m = w * 16 + lg * 4 + r;
                    if (t > m) s[tn][r] = -1e9f;
                }
            }
        }

        // online softmax: each row lives on 16 lanes (same lg group)
        for (int r = 0; r < 4; ++r) {
            float tm = fmaxf(fmaxf(s[0][r], s[1][r]), fmaxf(s[2][r], s[3][r]));
            for (int msk = 1; msk < 16; msk <<= 1) tm = fmaxf(tm, __shfl_xor(tm, msk, 64));
            float mnew = fmaxf(mrun[r], tm);
            float sc = __expf(mrun[r] - mnew);
            mrun[r] = mnew;
            float rs = 0.f;
            for (int tn = 0; tn < 4; ++tn) {
                float p = __expf(s[tn][r] - mnew);
                s[tn][r] = p;
                rs += p;
            }
            for (int msk = 1; msk < 16; msk <<= 1) rs += __shfl_xor(rs, msk, 64);
            lrun[r] = lrun[r] * sc + rs;
            for (int dn = 0; dn < 4; ++dn) oacc[dn][r] *= sc;
        }

        // P -> LDS (per wave) for A-fragment relayout
        for (int tn = 0; tn < 4; ++tn)
            for (int r = 0; r < 4; ++r)
                Pl[w][lg * 4 + r][tn * 16 + lr] = f2bf(s[tn][r]);

        // O += P V
        for (int kk = 0; kk < 2; ++kk) {
            bf16x8 pf = *(const bf16x8*)&Pl[w][lr][kk * 32 + lg * 8];
            for (int dn = 0; dn < 4; ++dn) {
                bf16x8 vf = *(const bf16x8*)&Vt[dn * 16 + lr][kk * 32 + lg * 8];
                oacc[dn] = __builtin_amdgcn_mfma_f32_16x16x32_bf16(pf, vf, oacc[dn], 0, 0, 0);
            }
        }
        __syncthreads();  // before next tile overwrites K/V
    }

    // epilogue: normalize, merge heads into ctx [B*S, D_MODEL] bf16
    const int b = bh >> 4, h = bh & 15;
    for (int r = 0; r < 4; ++r) {
        float inv = 1.0f / lrun[r];
        int srow = qt * 64 + w * 16 + lg * 4 + r;
        for (int dn = 0; dn < 4; ++dn) {
            int col = h * 64 + dn * 16 + lr;
            ctx[((size_t)b * SEQ + srow) * D_MODEL + col] = f2bf(oacc[dn][r] * inv);
        }
    }
}

extern "C" void kernel_launch(void* const* d_in, const int* in_sizes, int n_in,
                              void* d_out, int out_size, void* d_ws, size_t ws_size,
                              hipStream_t stream) {
    const float* v  = (const float*)d_in[0];
    const float* k  = (const float*)d_in[1];
    const float* q  = (const float*)d_in[2];
    // d_in[3] = mask (implemented analytically as causal)
    const float* Wq = (const float*)d_in[4];
    const float* bq = (const float*)d_in[5];
    const float* Wk = (const float*)d_in[6];
    const float* bk = (const float*)d_in[7];
    const float* Wv = (const float*)d_in[8];
    const float* bv = (const float*)d_in[9];
    const float* Wo = (const float*)d_in[10];
    const float* bo = (const float*)d_in[11];

    unsigned short* Qh  = (unsigned short*)d_ws;
    unsigned short* Kh  = Qh + (size_t)NTOK * D_MODEL;
    unsigned short* Vh  = Kh + (size_t)NTOK * D_MODEL;
    unsigned short* ctx = Vh + (size_t)NTOK * D_MODEL;
    // total ws use: 4 * 8 MB = 32 MB

    dim3 ggrid(D_MODEL / 128, NTOK / 128);  // (8, 32)
    gemm_bt<true, 0><<<ggrid, 256, 0, stream>>>(q, Wq, bq, Qh, NTOK, D_MODEL, D_MODEL);
    gemm_bt<true, 0><<<ggrid, 256, 0, stream>>>(k, Wk, bk, Kh, NTOK, D_MODEL, D_MODEL);
    gemm_bt<true, 0><<<ggrid, 256, 0, stream>>>(v, Wv, bv, Vh, NTOK, D_MODEL, D_MODEL);

    attn_causal<<<dim3(SEQ / 64, BATCH * NHEADS), 256, 0, stream>>>(Qh, Kh, Vh, ctx);

    gemm_bt<false, 1><<<ggrid, 256, 0, stream>>>(ctx, Wo, bo, (float*)d_out,
                                                 NTOK, D_MODEL, D_MODEL);
}

// Round 2
// 176.349 us; speedup vs baseline: 3.0046x; 3.0046x over previous
//
#include <hip/hip_runtime.h>
#include <hip/hip_bf16.h>

#define D_MODEL 1024
#define NHEADS 16
#define DEPTH 64
#define BATCH 2
#define SEQ 2048
#define NTOK (BATCH * SEQ)   // 4096

typedef short bf16x8 __attribute__((ext_vector_type(8)));
typedef float f32x4 __attribute__((ext_vector_type(4)));
typedef unsigned short ushortx8 __attribute__((ext_vector_type(8)));

using gas_ptr = const __attribute__((address_space(1))) unsigned int*;
using las_ptr = __attribute__((address_space(3))) unsigned int*;

__device__ __forceinline__ unsigned short f2bf(float f) {
    union { float f; unsigned u; } v; v.f = f;
    unsigned r = v.u + 0x7fffu + ((v.u >> 16) & 1u);
    return (unsigned short)(r >> 16);
}

// async global->LDS, 16B per lane; LDS dest = wave-uniform base + lane*16
__device__ __forceinline__ void gload16(const void* g, void* l) {
    __builtin_amdgcn_global_load_lds((gas_ptr)g, (las_ptr)l, 16, 0, 0);
}

// ---------------- prep: fp32 -> bf16 for activations + weights ----------------
__global__ __launch_bounds__(256) void convert_bf16(
    const float* __restrict__ q, const float* __restrict__ k, const float* __restrict__ v,
    const float* __restrict__ wq, const float* __restrict__ wk,
    const float* __restrict__ wv, const float* __restrict__ wo,
    unsigned short* __restrict__ qb, unsigned short* __restrict__ kb,
    unsigned short* __restrict__ vb,
    unsigned short* __restrict__ wqb, unsigned short* __restrict__ wkb,
    unsigned short* __restrict__ wvb, unsigned short* __restrict__ wob)
{
    const int ACT = (NTOK * D_MODEL) / 8;      // 524288 vec8 units
    const int WT  = (D_MODEL * D_MODEL) / 8;   // 131072
    const int total = 3 * ACT + 4 * WT;        // 2097152
    for (int i = blockIdx.x * 256 + threadIdx.x; i < total; i += gridDim.x * 256) {
        const float* s; unsigned short* d; int off;
        if (i < ACT)            { s = q; d = qb; off = i; }
        else if (i < 2 * ACT)   { s = k; d = kb; off = i - ACT; }
        else if (i < 3 * ACT)   { s = v; d = vb; off = i - 2 * ACT; }
        else {
            int j = i - 3 * ACT;
            int wsel = j >> 17;  off = j & (WT - 1);
            s = (wsel == 0) ? wq : (wsel == 1) ? wk : (wsel == 2) ? wv : wo;
            d = (wsel == 0) ? wqb : (wsel == 1) ? wkb : (wsel == 2) ? wvb : wob;
        }
        float4 a = ((const float4*)s)[off * 2];
        float4 b = ((const float4*)s)[off * 2 + 1];
        ushortx8 r;
        r[0] = f2bf(a.x); r[1] = f2bf(a.y); r[2] = f2bf(a.z); r[3] = f2bf(a.w);
        r[4] = f2bf(b.x); r[5] = f2bf(b.y); r[6] = f2bf(b.z); r[7] = f2bf(b.w);
        ((ushortx8*)d)[off] = r;
    }
}

// ---------------- m97-structure GEMM: C[M,N] = A[M,K] * B[N,K]^T + bias --------
// IT: per-wave row-fragments (IT=4 -> BM=128, IT=2 -> BM=64). BN=128, BK=64.
// DEST 0: bf16 head-split [B,H,S,DEPTH]; DEST 1: fp32 flat [M,N].
// QKV: select A/B/bias/C by blockIdx.z.
template<int IT, int DEST, bool QKV>
__global__ __launch_bounds__(256) void gemm_bf16(
    const unsigned short* __restrict__ A0, const unsigned short* __restrict__ A1,
    const unsigned short* __restrict__ A2,
    const unsigned short* __restrict__ B0, const unsigned short* __restrict__ B1,
    const unsigned short* __restrict__ B2,
    const float* __restrict__ bias0, const float* __restrict__ bias1,
    const float* __restrict__ bias2,
    void* __restrict__ C0, void* __restrict__ C1, void* __restrict__ C2,
    int M, int N, int K)
{
    constexpr int BM = IT * 32;
    constexpr int WROWS = IT * 16;            // per-wave row span
    __shared__ unsigned short As[BM * 64];    // linear row-major, row stride 64
    __shared__ unsigned short Bs[128 * 64];

    const unsigned short* A = A0; const unsigned short* Bw = B0;
    const float* bias = bias0;    void* Cp = C0;
    if (QKV) {
        int z = blockIdx.z;
        if (z == 1) { A = A1; Bw = B1; bias = bias1; Cp = C1; }
        else if (z == 2) { A = A2; Bw = B2; bias = bias2; Cp = C2; }
    }

    const int tid  = threadIdx.x;
    const int lane = tid & 63;
    const int w    = tid >> 6;
    const int wu   = __builtin_amdgcn_readfirstlane(w);
    const int wr   = w >> 1, wc = w & 1;
    const int lr   = lane & 15, lg = lane >> 4;

    const int row0 = blockIdx.y * BM;
    const int n0   = blockIdx.x * 128;

    // staging: chunk c, wave w covers LDS elements [(c*4+w)*512, +512); lane does 8
    const int srow = lane >> 3, scol = (lane & 7) * 8;
    const unsigned short* gA[IT];
    for (int c = 0; c < IT; ++c)
        gA[c] = A + (size_t)(row0 + (c * 4 + wu) * 8 + srow) * K + scol;
    const unsigned short* gB[4];
    for (int c = 0; c < 4; ++c)
        gB[c] = Bw + (size_t)(n0 + (c * 4 + wu) * 8 + srow) * K + scol;

    f32x4 acc[IT][4];
    for (int i = 0; i < IT; ++i)
        for (int j = 0; j < 4; ++j)
            for (int r = 0; r < 4; ++r) acc[i][j][r] = 0.f;

    for (int kt = 0; kt < K; kt += 64) {
        for (int c = 0; c < IT; ++c)
            gload16(gA[c] + kt, &As[(c * 4 + wu) * 512]);
        for (int c = 0; c < 4; ++c)
            gload16(gB[c] + kt, &Bs[(c * 4 + wu) * 512]);
        __syncthreads();

        bf16x8 af[IT][2], bfr[4][2];
        for (int i = 0; i < IT; ++i)
            for (int kk = 0; kk < 2; ++kk)
                af[i][kk] = *(const bf16x8*)&As[(wr * WROWS + i * 16 + lr) * 64 + kk * 32 + lg * 8];
        for (int j = 0; j < 4; ++j)
            for (int kk = 0; kk < 2; ++kk)
                bfr[j][kk] = *(const bf16x8*)&Bs[(wc * 64 + j * 16 + lr) * 64 + kk * 32 + lg * 8];
        for (int kk = 0; kk < 2; ++kk)
            for (int i = 0; i < IT; ++i)
                for (int j = 0; j < 4; ++j)
                    acc[i][j] = __builtin_amdgcn_mfma_f32_16x16x32_bf16(
                        af[i][kk], bfr[j][kk], acc[i][j], 0, 0, 0);
        __syncthreads();
    }

    for (int i = 0; i < IT; ++i) {
        for (int j = 0; j < 4; ++j) {
            int gcol = n0 + wc * 64 + j * 16 + lr;
            float bv = bias[gcol];
            for (int r = 0; r < 4; ++r) {
                int grow = row0 + wr * WROWS + i * 16 + lg * 4 + r;
                float val = acc[i][j][r] + bv;
                if (DEST == 0) {
                    int b = grow >> 11, s = grow & (SEQ - 1);
                    int h = gcol >> 6, dh = gcol & 63;
                    ((unsigned short*)Cp)[(((size_t)b * NHEADS + h) * SEQ + s) * DEPTH + dh]
                        = f2bf(val);
                } else {
                    ((float*)Cp)[(size_t)grow * N + gcol] = val;
                }
            }
        }
    }
}

// -------- causal flash attention: 8 waves, 128 Q-rows/block, KV tiles of 64 ----
__global__ __launch_bounds__(512) void attn_causal(
    const unsigned short* __restrict__ Qh, const unsigned short* __restrict__ Kh,
    const unsigned short* __restrict__ Vh, unsigned short* __restrict__ ctx)
{
    // XCD-chunked decode: blocks with equal (id%32)=bh land on the same XCD set
    const int id = blockIdx.x;
    const int bh = id & 31;
    const int qt = 15 - (id >> 5);       // big tiles first (load balance)

    const int tid  = threadIdx.x;
    const int w    = tid >> 6;           // 0..7, wave rows w*16..w*16+15
    const int lane = tid & 63;
    const int lr   = lane & 15, lg = lane >> 4;

    __shared__ unsigned short Kl[64][72];     // +8 pad
    __shared__ unsigned short Vt[64][72];     // transposed: Vt[d][t]
    __shared__ unsigned short Pl[8][16][72];  // per-wave P tile

    const int qrow0w = qt * 128 + w * 16;
    const unsigned short* Qbase = Qh + ((size_t)bh * SEQ + qt * 128) * DEPTH;
    const unsigned short* Kbase = Kh + (size_t)bh * SEQ * DEPTH;
    const unsigned short* Vbase = Vh + (size_t)bh * SEQ * DEPTH;

    bf16x8 qf[2];
    for (int kk = 0; kk < 2; ++kk)
        qf[kk] = *(const bf16x8*)&Qbase[(size_t)(w * 16 + lr) * DEPTH + kk * 32 + lg * 8];

    f32x4 oacc[4];
    for (int dn = 0; dn < 4; ++dn)
        for (int r = 0; r < 4; ++r) oacc[dn][r] = 0.f;
    float mrun[4] = {-1e30f, -1e30f, -1e30f, -1e30f};
    float lrun[4] = {0.f, 0.f, 0.f, 0.f};

    const int jmax = 2 * qt + 1;
    for (int jt = 0; jt <= jmax; ++jt) {
        const unsigned short* Kt = Kbase + (size_t)jt * 64 * DEPTH;
        const unsigned short* Vg = Vbase + (size_t)jt * 64 * DEPTH;

        // stage K [64][64]: 512 threads x 1 vec8
        {
            int r = tid >> 3, col = (tid & 7) * 8;
            *(ushortx8*)&Kl[r][col] = *(const ushortx8*)&Kt[r * 64 + col];
        }
        // stage V transposed: thread handles V[t][d0..d0+7]
        {
            int t = tid & 63, d0 = (tid >> 6) * 8;
            ushortx8 v0 = *(const ushortx8*)&Vg[t * 64 + d0];
            for (int i = 0; i < 8; ++i) Vt[d0 + i][t] = v0[i];
        }
        __syncthreads();

        const bool active = (jt * 64) <= (qrow0w + 15);
        if (active) {
            // S = Q K^T / 8
            f32x4 s[4];
            for (int tn = 0; tn < 4; ++tn) {
                f32x4 a;
                for (int r = 0; r < 4; ++r) a[r] = 0.f;
                for (int kk = 0; kk < 2; ++kk) {
                    bf16x8 kf = *(const bf16x8*)&Kl[tn * 16 + lr][kk * 32 + lg * 8];
                    a = __builtin_amdgcn_mfma_f32_16x16x32_bf16(qf[kk], kf, a, 0, 0, 0);
                }
                for (int r = 0; r < 4; ++r) s[tn][r] = a[r] * 0.125f;
            }

            if (jt * 64 + 63 > qrow0w) {   // mask only near the diagonal
                for (int tn = 0; tn < 4; ++tn) {
                    int t = jt * 64 + tn * 16 + lr;
                    for (int r = 0; r < 4; ++r) {
                        int m = qrow0w + lg * 4 + r;
                        if (t > m) s[tn][r] = -1e9f;
                    }
                }
            }

            // online softmax (row lives on the 16 lanes sharing lg)
            for (int r = 0; r < 4; ++r) {
                float tm = fmaxf(fmaxf(s[0][r], s[1][r]), fmaxf(s[2][r], s[3][r]));
                for (int msk = 1; msk < 16; msk <<= 1) tm = fmaxf(tm, __shfl_xor(tm, msk, 64));
                float mnew = fmaxf(mrun[r], tm);
                float sc = __expf(mrun[r] - mnew);
                mrun[r] = mnew;
                float rs = 0.f;
                for (int tn = 0; tn < 4; ++tn) {
                    float p = __expf(s[tn][r] - mnew);
                    s[tn][r] = p;
                    rs += p;
                }
                for (int msk = 1; msk < 16; msk <<= 1) rs += __shfl_xor(rs, msk, 64);
                lrun[r] = lrun[r] * sc + rs;
                for (int dn = 0; dn < 4; ++dn) oacc[dn][r] *= sc;
            }

            // P -> per-wave LDS for A-fragment relayout
            for (int tn = 0; tn < 4; ++tn)
                for (int r = 0; r < 4; ++r)
                    Pl[w][lg * 4 + r][tn * 16 + lr] = f2bf(s[tn][r]);

            // O += P V
            for (int kk = 0; kk < 2; ++kk) {
                bf16x8 pf = *(const bf16x8*)&Pl[w][lr][kk * 32 + lg * 8];
                for (int dn = 0; dn < 4; ++dn) {
                    bf16x8 vf = *(const bf16x8*)&Vt[dn * 16 + lr][kk * 32 + lg * 8];
                    oacc[dn] = __builtin_amdgcn_mfma_f32_16x16x32_bf16(pf, vf, oacc[dn], 0, 0, 0);
                }
            }
        }
        __syncthreads();
    }

    const int b = bh >> 4, h = bh & 15;
    for (int r = 0; r < 4; ++r) {
        float inv = 1.0f / lrun[r];
        int srow = qrow0w + lg * 4 + r;
        for (int dn = 0; dn < 4; ++dn) {
            int col = h * 64 + dn * 16 + lr;
            ctx[((size_t)b * SEQ + srow) * D_MODEL + col] = f2bf(oacc[dn][r] * inv);
        }
    }
}

extern "C" void kernel_launch(void* const* d_in, const int* in_sizes, int n_in,
                              void* d_out, int out_size, void* d_ws, size_t ws_size,
                              hipStream_t stream) {
    const float* v  = (const float*)d_in[0];
    const float* k  = (const float*)d_in[1];
    const float* q  = (const float*)d_in[2];
    // d_in[3] = mask (causal, implemented analytically)
    const float* Wq = (const float*)d_in[4];
    const float* bq = (const float*)d_in[5];
    const float* Wk = (const float*)d_in[6];
    const float* bk = (const float*)d_in[7];
    const float* Wv = (const float*)d_in[8];
    const float* bv = (const float*)d_in[9];
    const float* Wo = (const float*)d_in[10];
    const float* bo = (const float*)d_in[11];

    char* ws = (char*)d_ws;
    const size_t MB = 1024 * 1024;
    unsigned short* Qb  = (unsigned short*)(ws + 0);        // 8 MB (later aliased by ctx)
    unsigned short* Kb  = (unsigned short*)(ws + 8  * MB);
    unsigned short* Vb  = (unsigned short*)(ws + 16 * MB);
    unsigned short* Wqb = (unsigned short*)(ws + 24 * MB);  // 2 MB each
    unsigned short* Wkb = (unsigned short*)(ws + 26 * MB);
    unsigned short* Wvb = (unsigned short*)(ws + 28 * MB);
    unsigned short* Wob = (unsigned short*)(ws + 30 * MB);
    unsigned short* Qh  = (unsigned short*)(ws + 32 * MB);  // 8 MB each
    unsigned short* Kh  = (unsigned short*)(ws + 40 * MB);
    unsigned short* Vh  = (unsigned short*)(ws + 48 * MB);
    unsigned short* ctx = Qb;   // Qb dead once projections finish

    convert_bf16<<<2048, 256, 0, stream>>>(q, k, v, Wq, Wk, Wv, Wo,
                                           Qb, Kb, Vb, Wqb, Wkb, Wvb, Wob);

    // fused QKV projections: 768 blocks = 3/CU
    gemm_bf16<4, 0, true><<<dim3(8, 32, 3), 256, 0, stream>>>(
        Qb, Kb, Vb, Wqb, Wkb, Wvb, bq, bk, bv,
        (void*)Qh, (void*)Kh, (void*)Vh, NTOK, D_MODEL, D_MODEL);

    attn_causal<<<dim3(512), 512, 0, stream>>>(Qh, Kh, Vh, ctx);

    // output projection: BM=64 -> 512 blocks = 2/CU
    gemm_bf16<2, 1, false><<<dim3(8, 64), 256, 0, stream>>>(
        ctx, nullptr, nullptr, Wob, nullptr, nullptr, bo, nullptr, nullptr,
        d_out, nullptr, nullptr, NTOK, D_MODEL, D_MODEL);
}

// Round 3
// 172.070 us; speedup vs baseline: 3.0793x; 1.0249x over previous
//
#include <hip/hip_runtime.h>
#include <hip/hip_bf16.h>

#define D_MODEL 1024
#define NHEADS 16
#define DEPTH 64
#define BATCH 2
#define SEQ 2048
#define NTOK (BATCH * SEQ)   // 4096

typedef short bf16x8 __attribute__((ext_vector_type(8)));
typedef float f32x4 __attribute__((ext_vector_type(4)));
typedef unsigned short ushortx8 __attribute__((ext_vector_type(8)));

using gas_ptr = const __attribute__((address_space(1))) unsigned int*;
using las_ptr = __attribute__((address_space(3))) unsigned int*;

__device__ __forceinline__ unsigned short f2bf(float f) {
    union { float f; unsigned u; } v; v.f = f;
    unsigned r = v.u + 0x7fffu + ((v.u >> 16) & 1u);
    return (unsigned short)(r >> 16);
}

// async global->LDS, 16B per lane; LDS dest = wave-uniform base + lane*16
__device__ __forceinline__ void gload16(const void* g, void* l) {
    __builtin_amdgcn_global_load_lds((gas_ptr)g, (las_ptr)l, 16, 0, 0);
}

// ---------------- prep: fp32 -> bf16 for activations + weights ----------------
// Wq is pre-scaled by 0.125 (1/sqrt(DEPTH)) so attention skips the scale.
__global__ __launch_bounds__(256) void convert_bf16(
    const float* __restrict__ q, const float* __restrict__ k, const float* __restrict__ v,
    const float* __restrict__ wq, const float* __restrict__ wk,
    const float* __restrict__ wv, const float* __restrict__ wo,
    unsigned short* __restrict__ qb, unsigned short* __restrict__ kb,
    unsigned short* __restrict__ vb,
    unsigned short* __restrict__ wqb, unsigned short* __restrict__ wkb,
    unsigned short* __restrict__ wvb, unsigned short* __restrict__ wob)
{
    const int ACT = (NTOK * D_MODEL) / 8;      // 524288 vec8 units
    const int WT  = (D_MODEL * D_MODEL) / 8;   // 131072
    const int total = 3 * ACT + 4 * WT;        // 2097152
    for (int i = blockIdx.x * 256 + threadIdx.x; i < total; i += gridDim.x * 256) {
        const float* s; unsigned short* d; int off; float sc = 1.f;
        if (i < ACT)            { s = q; d = qb; off = i; }
        else if (i < 2 * ACT)   { s = k; d = kb; off = i - ACT; }
        else if (i < 3 * ACT)   { s = v; d = vb; off = i - 2 * ACT; }
        else {
            int j = i - 3 * ACT;
            int wsel = j >> 17;  off = j & (WT - 1);
            s = (wsel == 0) ? wq : (wsel == 1) ? wk : (wsel == 2) ? wv : wo;
            d = (wsel == 0) ? wqb : (wsel == 1) ? wkb : (wsel == 2) ? wvb : wob;
            if (wsel == 0) sc = 0.125f;
        }
        float4 a = ((const float4*)s)[off * 2];
        float4 b = ((const float4*)s)[off * 2 + 1];
        ushortx8 r;
        r[0] = f2bf(a.x * sc); r[1] = f2bf(a.y * sc);
        r[2] = f2bf(a.z * sc); r[3] = f2bf(a.w * sc);
        r[4] = f2bf(b.x * sc); r[5] = f2bf(b.y * sc);
        r[6] = f2bf(b.z * sc); r[7] = f2bf(b.w * sc);
        ((ushortx8*)d)[off] = r;
    }
}

// ---------------- m97-structure GEMM: C[M,N] = A[M,K] * B[N,K]^T + bias --------
template<int IT, int DEST, bool QKV>
__global__ __launch_bounds__(256) void gemm_bf16(
    const unsigned short* __restrict__ A0, const unsigned short* __restrict__ A1,
    const unsigned short* __restrict__ A2,
    const unsigned short* __restrict__ B0, const unsigned short* __restrict__ B1,
    const unsigned short* __restrict__ B2,
    const float* __restrict__ bias0, const float* __restrict__ bias1,
    const float* __restrict__ bias2,
    void* __restrict__ C0, void* __restrict__ C1, void* __restrict__ C2,
    int M, int N, int K)
{
    constexpr int BM = IT * 32;
    constexpr int WROWS = IT * 16;
    __shared__ unsigned short As[BM * 64];
    __shared__ unsigned short Bs[128 * 64];

    const unsigned short* A = A0; const unsigned short* Bw = B0;
    const float* bias = bias0;    void* Cp = C0;
    float bsc = 1.f;
    if (QKV) {
        int z = blockIdx.z;
        if (z == 0) bsc = 0.125f;   // Wq pre-scaled; scale bias to match
        if (z == 1) { A = A1; Bw = B1; bias = bias1; Cp = C1; }
        else if (z == 2) { A = A2; Bw = B2; bias = bias2; Cp = C2; }
    }

    const int tid  = threadIdx.x;
    const int lane = tid & 63;
    const int w    = tid >> 6;
    const int wu   = __builtin_amdgcn_readfirstlane(w);
    const int wr   = w >> 1, wc = w & 1;
    const int lr   = lane & 15, lg = lane >> 4;

    const int row0 = blockIdx.y * BM;
    const int n0   = blockIdx.x * 128;

    const int srow = lane >> 3, scol = (lane & 7) * 8;
    const unsigned short* gA[IT];
    for (int c = 0; c < IT; ++c)
        gA[c] = A + (size_t)(row0 + (c * 4 + wu) * 8 + srow) * K + scol;
    const unsigned short* gB[4];
    for (int c = 0; c < 4; ++c)
        gB[c] = Bw + (size_t)(n0 + (c * 4 + wu) * 8 + srow) * K + scol;

    f32x4 acc[IT][4];
    for (int i = 0; i < IT; ++i)
        for (int j = 0; j < 4; ++j)
            for (int r = 0; r < 4; ++r) acc[i][j][r] = 0.f;

    for (int kt = 0; kt < K; kt += 64) {
        for (int c = 0; c < IT; ++c)
            gload16(gA[c] + kt, &As[(c * 4 + wu) * 512]);
        for (int c = 0; c < 4; ++c)
            gload16(gB[c] + kt, &Bs[(c * 4 + wu) * 512]);
        __syncthreads();

        bf16x8 af[IT][2], bfr[4][2];
        for (int i = 0; i < IT; ++i)
            for (int kk = 0; kk < 2; ++kk)
                af[i][kk] = *(const bf16x8*)&As[(wr * WROWS + i * 16 + lr) * 64 + kk * 32 + lg * 8];
        for (int j = 0; j < 4; ++j)
            for (int kk = 0; kk < 2; ++kk)
                bfr[j][kk] = *(const bf16x8*)&Bs[(wc * 64 + j * 16 + lr) * 64 + kk * 32 + lg * 8];
        for (int kk = 0; kk < 2; ++kk)
            for (int i = 0; i < IT; ++i)
                for (int j = 0; j < 4; ++j)
                    acc[i][j] = __builtin_amdgcn_mfma_f32_16x16x32_bf16(
                        af[i][kk], bfr[j][kk], acc[i][j], 0, 0, 0);
        __syncthreads();
    }

    for (int i = 0; i < IT; ++i) {
        for (int j = 0; j < 4; ++j) {
            int gcol = n0 + wc * 64 + j * 16 + lr;
            float bv = bias[gcol] * bsc;
            for (int r = 0; r < 4; ++r) {
                int grow = row0 + wr * WROWS + i * 16 + lg * 4 + r;
                float val = acc[i][j][r] + bv;
                if (DEST == 0) {
                    int b = grow >> 11, s = grow & (SEQ - 1);
                    int h = gcol >> 6, dh = gcol & 63;
                    ((unsigned short*)Cp)[(((size_t)b * NHEADS + h) * SEQ + s) * DEPTH + dh]
                        = f2bf(val);
                } else {
                    ((float*)Cp)[(size_t)grow * N + gcol] = val;
                }
            }
        }
    }
}

// -------- causal flash attention: 8 waves, 128 Q-rows/block, KV tiles of 64 ----
// Double-buffered: K via global_load_lds + XOR swizzle (both-sides), V via
// reg-staged async-split transpose. One barrier per tile.
__global__ __launch_bounds__(512) void attn_causal(
    const unsigned short* __restrict__ Qh, const unsigned short* __restrict__ Kh,
    const unsigned short* __restrict__ Vh, unsigned short* __restrict__ ctx)
{
    const int id = blockIdx.x;
    const int bh = id & 31;
    const int qt = 15 - (id >> 5);       // big tiles first

    const int tid  = threadIdx.x;
    const int w    = tid >> 6;
    const int wu   = __builtin_amdgcn_readfirstlane(w);
    const int lane = tid & 63;
    const int lr   = lane & 15, lg = lane >> 4;

    __shared__ unsigned short Ksh[2][64 * 64];   // linear, swizzled content
    __shared__ unsigned short Vsh[2][64][72];    // transposed Vt[d][t], +8 pad
    __shared__ unsigned short Pl[8][16][72];

    const int qrow0w = qt * 128 + w * 16;
    const unsigned short* Qbase = Qh + ((size_t)bh * SEQ + qt * 128) * DEPTH;
    const unsigned short* Kbase = Kh + (size_t)bh * SEQ * DEPTH;
    const unsigned short* Vbase = Vh + (size_t)bh * SEQ * DEPTH;

    // K staging: thread covers physical 16B chunk pc = tid of the [64][64] tile.
    // Inverse-swizzled global source so readers can XOR on the way out.
    const int kt_row = tid >> 3;                       // tile row t
    const int kcs    = (tid & 7) ^ (kt_row & 7);       // source chunk
    const unsigned short* kSrc = Kbase + kt_row * 64 + kcs * 8;
    // V staging: thread loads V[t][d0..d0+7], writes transposed.
    const int vt_t = tid & 63, vd0 = (tid >> 6) * 8;
    const unsigned short* vSrc = Vbase + vt_t * 64 + vd0;

    bf16x8 qf[2];
    for (int kk = 0; kk < 2; ++kk)
        qf[kk] = *(const bf16x8*)&Qbase[(size_t)(w * 16 + lr) * DEPTH + kk * 32 + lg * 8];

    f32x4 oacc[4];
    for (int dn = 0; dn < 4; ++dn)
        for (int r = 0; r < 4; ++r) oacc[dn][r] = 0.f;
    float mrun[4] = {-1e30f, -1e30f, -1e30f, -1e30f};
    float lrun[4] = {0.f, 0.f, 0.f, 0.f};

    // prologue: stage tile 0 into buffer 0
    gload16(kSrc, &Ksh[0][wu * 512]);
    {
        ushortx8 vr = *(const ushortx8*)vSrc;
        asm volatile("s_waitcnt vmcnt(0)" ::: "memory");
        for (int i = 0; i < 8; ++i) Vsh[0][vd0 + i][vt_t] = vr[i];
    }
    __syncthreads();

    const int jmax = 2 * qt + 1;
    int cur = 0;
    for (int jt = 0; jt <= jmax; ++jt) {
        const int nxt = cur ^ 1;
        ushortx8 vr;
        if (jt < jmax) {
            gload16(kSrc + (size_t)(jt + 1) * 64 * DEPTH, &Ksh[nxt][wu * 512]);
            vr = *(const ushortx8*)(vSrc + (size_t)(jt + 1) * 64 * DEPTH);
        }

        const bool active = (jt * 64) <= (qrow0w + 15);
        if (active) {
            const unsigned short* Kc = &Ksh[cur][0];
            // S = Q K^T  (scale folded into Wq)
            f32x4 s[4];
            const int swz = lr & 7;
            for (int tn = 0; tn < 4; ++tn) {
                f32x4 a;
                for (int r = 0; r < 4; ++r) a[r] = 0.f;
                for (int kk = 0; kk < 2; ++kk) {
                    bf16x8 kf = *(const bf16x8*)&Kc[(tn * 16 + lr) * 64 + ((kk * 4 + lg) ^ swz) * 8];
                    a = __builtin_amdgcn_mfma_f32_16x16x32_bf16(qf[kk], kf, a, 0, 0, 0);
                }
                s[tn] = a;
            }

            if (jt * 64 + 63 > qrow0w) {   // mask only near the diagonal
                for (int tn = 0; tn < 4; ++tn) {
                    int t = jt * 64 + tn * 16 + lr;
                    for (int r = 0; r < 4; ++r) {
                        int m = qrow0w + lg * 4 + r;
                        if (t > m) s[tn][r] = -1e9f;
                    }
                }
            }

            // online softmax (row lives on the 16 lanes sharing lg)
            for (int r = 0; r < 4; ++r) {
                float tm = fmaxf(fmaxf(s[0][r], s[1][r]), fmaxf(s[2][r], s[3][r]));
                for (int msk = 1; msk < 16; msk <<= 1) tm = fmaxf(tm, __shfl_xor(tm, msk, 64));
                float mnew = fmaxf(mrun[r], tm);
                float sc = __expf(mrun[r] - mnew);
                mrun[r] = mnew;
                float rs = 0.f;
                for (int tn = 0; tn < 4; ++tn) {
                    float p = __expf(s[tn][r] - mnew);
                    s[tn][r] = p;
                    rs += p;
                }
                for (int msk = 1; msk < 16; msk <<= 1) rs += __shfl_xor(rs, msk, 64);
                lrun[r] = lrun[r] * sc + rs;
                for (int dn = 0; dn < 4; ++dn) oacc[dn][r] *= sc;
            }

            // P -> per-wave LDS for A-fragment relayout
            for (int tn = 0; tn < 4; ++tn)
                for (int r = 0; r < 4; ++r)
                    Pl[w][lg * 4 + r][tn * 16 + lr] = f2bf(s[tn][r]);

            // O += P V
            for (int kk = 0; kk < 2; ++kk) {
                bf16x8 pf = *(const bf16x8*)&Pl[w][lr][kk * 32 + lg * 8];
                for (int dn = 0; dn < 4; ++dn) {
                    bf16x8 vf = *(const bf16x8*)&Vsh[cur][dn * 16 + lr][kk * 32 + lg * 8];
                    oacc[dn] = __builtin_amdgcn_mfma_f32_16x16x32_bf16(pf, vf, oacc[dn], 0, 0, 0);
                }
            }
        }

        if (jt < jmax) {
            asm volatile("s_waitcnt vmcnt(0)" ::: "memory");
            for (int i = 0; i < 8; ++i) Vsh[nxt][vd0 + i][vt_t] = vr[i];
        }
        __syncthreads();
        cur = nxt;
    }

    const int b = bh >> 4, h = bh & 15;
    for (int r = 0; r < 4; ++r) {
        float inv = 1.0f / lrun[r];
        int srow = qrow0w + lg * 4 + r;
        for (int dn = 0; dn < 4; ++dn) {
            int col = h * 64 + dn * 16 + lr;
            ctx[((size_t)b * SEQ + srow) * D_MODEL + col] = f2bf(oacc[dn][r] * inv);
        }
    }
}

extern "C" void kernel_launch(void* const* d_in, const int* in_sizes, int n_in,
                              void* d_out, int out_size, void* d_ws, size_t ws_size,
                              hipStream_t stream) {
    const float* v  = (const float*)d_in[0];
    const float* k  = (const float*)d_in[1];
    const float* q  = (const float*)d_in[2];
    // d_in[3] = mask (causal, implemented analytically)
    const float* Wq = (const float*)d_in[4];
    const float* bq = (const float*)d_in[5];
    const float* Wk = (const float*)d_in[6];
    const float* bk = (const float*)d_in[7];
    const float* Wv = (const float*)d_in[8];
    const float* bv = (const float*)d_in[9];
    const float* Wo = (const float*)d_in[10];
    const float* bo = (const float*)d_in[11];

    char* ws = (char*)d_ws;
    const size_t MB = 1024 * 1024;
    unsigned short* Qb  = (unsigned short*)(ws + 0);        // 8 MB (aliased by ctx later)
    unsigned short* Kb  = (unsigned short*)(ws + 8  * MB);
    unsigned short* Vb  = (unsigned short*)(ws + 16 * MB);
    unsigned short* Wqb = (unsigned short*)(ws + 24 * MB);  // 2 MB each
    unsigned short* Wkb = (unsigned short*)(ws + 26 * MB);
    unsigned short* Wvb = (unsigned short*)(ws + 28 * MB);
    unsigned short* Wob = (unsigned short*)(ws + 30 * MB);
    unsigned short* Qh  = (unsigned short*)(ws + 32 * MB);  // 8 MB each
    unsigned short* Kh  = (unsigned short*)(ws + 40 * MB);
    unsigned short* Vh  = (unsigned short*)(ws + 48 * MB);
    unsigned short* ctx = Qb;   // Qb dead once projections finish

    convert_bf16<<<2048, 256, 0, stream>>>(q, k, v, Wq, Wk, Wv, Wo,
                                           Qb, Kb, Vb, Wqb, Wkb, Wvb, Wob);

    gemm_bf16<4, 0, true><<<dim3(8, 32, 3), 256, 0, stream>>>(
        Qb, Kb, Vb, Wqb, Wkb, Wvb, bq, bk, bv,
        (void*)Qh, (void*)Kh, (void*)Vh, NTOK, D_MODEL, D_MODEL);

    attn_causal<<<dim3(512), 512, 0, stream>>>(Qh, Kh, Vh, ctx);

    gemm_bf16<2, 1, false><<<dim3(8, 64), 256, 0, stream>>>(
        ctx, nullptr, nullptr, Wob, nullptr, nullptr, bo, nullptr, nullptr,
        d_out, nullptr, nullptr, NTOK, D_MODEL, D_MODEL);
}